// Round 11
// baseline (160.687 us; speedup 1.0000x reference)
//
#include <hip/hip_runtime.h>

// GIN 2-layer forward.  N=100000 nodes, E=1600000 edges, NF=32, HC=NC=64.
// R11: XCD-sliced gather. R8-R10 showed the fused gather pinned at 42-46us,
// invariant to ILP/occupancy -> outstanding-miss x latency bound, table
// misses L2 (FETCH 82MB vs 12.8MB table). Fix: slice-major feature tables
// (4 slices; 1.6/3.2MB per slice region fits 4MB per-XCD L2), gather grid
// bid=tile*4+slice so bid%8 XCD mapping gives each XCD ONE slice. Gather and
// MFMA-MLP split into separate kernels (z round-trip in bf16).

#define NFEAT 32
#define HID   64
#define NCLS  64

#define BSH   9                 // bucket = dst >> 9  (512 nodes per bucket)
#define BNODES 512
#define NBKT_MAX 256            // supports N <= 131072
#define BCAP  16384             // slots per bucket (mean 8192 for uniform E=1.6M)
#define ECAP  2048              // LDS-staged edges per 64-node tile

typedef unsigned int uint;
typedef unsigned short ushortT;
typedef __attribute__((ext_vector_type(8))) short bf16x8;   // 8 bf16 = 4 VGPR
typedef __attribute__((ext_vector_type(4))) float f32x4;

__device__ __forceinline__ int clampi(int v, int hi){ v = v < 0 ? 0 : v; return v > hi ? hi : v; }

// round-to-nearest-even f32 -> bf16 (as ushort)
__device__ __forceinline__ ushortT f2b(float f){
  uint u = __float_as_uint(f);
  u = (u + 0x7FFFu + ((u >> 16) & 1u)) >> 16;
  return (ushortT)u;
}
__device__ __forceinline__ float b2f_lo(uint u){ return __uint_as_float(u << 16); }
__device__ __forceinline__ float b2f_hi(uint u){ return __uint_as_float(u & 0xFFFF0000u); }
__device__ __forceinline__ uint pack2(float lo, float hi){
  return (uint)f2b(lo) | ((uint)f2b(hi) << 16);
}

// ---- k_prep: xb4 = bf16(x) slice-major; transposed bf16 weights; bktCnt=0 --
// xb4 layout: [4 slices][N][8 bf16 = 16B]; slice s = features s*8..s*8+7.

__global__ void k_prep(const float* __restrict__ x, uint4* __restrict__ xb4, int N,
                       const float* __restrict__ W1a, const float* __restrict__ W1b,
                       const float* __restrict__ W2a, const float* __restrict__ W2b,
                       ushortT* __restrict__ T1a, ushortT* __restrict__ T1b,
                       ushortT* __restrict__ T2a, ushortT* __restrict__ T2b,
                       int* __restrict__ bktCnt, int nbkt){
  int t = blockIdx.x*256 + threadIdx.x;
  if (t < N*4){
    int n = t >> 2, s = t & 3;
    const float* xr = x + (size_t)n*NFEAT + s*8;
    uint4 o;
    o.x = pack2(xr[0], xr[1]); o.y = pack2(xr[2], xr[3]);
    o.z = pack2(xr[4], xr[5]); o.w = pack2(xr[6], xr[7]);
    xb4[(size_t)s*N + n] = o;
  }
  if (t < nbkt) bktCnt[t] = 0;
  if (t < 14336){
    const float* W; ushortT* T; int K; int base;
    if      (t <  2048){ W=W1a; T=T1a; K=32; base=0;     }
    else if (t <  6144){ W=W1b; T=T1b; K=64; base=2048;  }
    else if (t < 10240){ W=W2a; T=T2a; K=64; base=6144;  }
    else               { W=W2b; T=T2b; K=64; base=10240; }
    int o = t - base;
    int k = o >> 6, c = o & 63;        // all matrices have 64 columns
    T[c*K + k] = f2b(W[o]);
  }
}

// ---- Pass A: bucket edges by dst>>9, packed val = (dstLow9<<17)|src --------

__global__ void k_bucket(const int* __restrict__ src, const int* __restrict__ dst,
                         int E, int N, int nbkt,
                         int* __restrict__ bktCnt, int* __restrict__ bktData){
  __shared__ int s_cnt[NBKT_MAX];
  __shared__ int s_base[NBKT_MAX];
  const int t = threadIdx.x;
  for (int j = t; j < nbkt; j += 256) s_cnt[j] = 0;
  __syncthreads();

  const int e0 = blockIdx.x * 4096;
  const int e1 = min(e0 + 4096, E);
  for (int e = e0 + t; e < e1; e += 256){
    int d = clampi(dst[e], N-1);
    atomicAdd(&s_cnt[d >> BSH], 1);
  }
  __syncthreads();
  for (int j = t; j < nbkt; j += 256){
    int c = s_cnt[j];
    s_base[j] = (c > 0) ? atomicAdd(&bktCnt[j], c) : 0;
    s_cnt[j] = 0;                     // reuse as local cursor
  }
  __syncthreads();
  for (int e = e0 + t; e < e1; e += 256){
    int d = clampi(dst[e], N-1);
    int s = clampi(src[e], N-1);
    int b = d >> BSH;
    int p = s_base[b] + atomicAdd(&s_cnt[b], 1);
    if (p < BCAP)                     // statistically unreachable; UB guard
      bktData[(size_t)b * BCAP + p] = ((d & (BNODES-1)) << 17) | s;
  }
}

// ---- Pass B: per-bucket CSR fill; bucket prefix computed in-block ----------

__global__ __launch_bounds__(BNODES)
void k_build(const int* __restrict__ bktCnt, const int* __restrict__ bktData,
             int nbkt, int* __restrict__ rowptr, int* __restrict__ eidx, int N){
  __shared__ int s_bs[NBKT_MAX];
  __shared__ int s_h[BNODES];
  __shared__ int s_cur[BNODES];
  const int b = blockIdx.x, t = threadIdx.x;

  if (t < NBKT_MAX) s_bs[t] = (t < nbkt) ? min(bktCnt[t], BCAP) : 0;
  __syncthreads();
  for (int off = 1; off < NBKT_MAX; off <<= 1){
    int add = 0;
    if (t < NBKT_MAX && t >= off) add = s_bs[t-off];
    __syncthreads();
    if (t < NBKT_MAX) s_bs[t] += add;
    __syncthreads();
  }
  const int cnt  = min(bktCnt[b], BCAP);
  const int base = s_bs[b] - cnt;     // exclusive prefix
  if (b == 0 && t == 0) rowptr[N] = s_bs[nbkt-1];
  const int* __restrict__ data = bktData + (size_t)b * BCAP;

  s_h[t] = 0;
  __syncthreads();
  for (int e = t; e < cnt; e += BNODES) atomicAdd(&s_h[data[e] >> 17], 1);
  __syncthreads();

  int deg = s_h[t];
  for (int off = 1; off < BNODES; off <<= 1){     // inclusive scan over nodes
    int add = (t >= off) ? s_h[t-off] : 0;
    __syncthreads();
    s_h[t] += add;
    __syncthreads();
  }
  int excl = s_h[t] - deg;
  int node = b * BNODES + t;
  if (node < N) rowptr[node] = base + excl;
  s_cur[t] = excl;
  __syncthreads();

  for (int e = t; e < cnt; e += BNODES){
    int val = data[e];
    int d = val >> 17;
    int p = atomicAdd(&s_cur[d], 1);
    eidx[base + p] = val & 0x1FFFF;
  }
}

// ---- k_gath<K>: sliced gather-aggregate ------------------------------------
// grid = ntile*4, bid = tile*4 + slice  (bid%8 -> XCD gets one slice).
// tb: slice-major table [4][N][K/4 bf16]; z out: [NP][K] bf16 (normal layout).
// block 256 = 64 nodes x 4 lanes. Lane L = q*SPLITW + sp:
//   K=32: QL=1 chunk, SPLITW=4 (4-way edge split, 16B/edge/lane)
//   K=64: QL=2 chunks, SPLITW=2 (2-way split, lane loads its 16B half)
// Predicated U=4 batches: 4 loads always in flight, tail masked via fmac.

template<int K>
__global__ __launch_bounds__(256)
void k_gath(const uint4* __restrict__ tb,
            const int* __restrict__ rowptr, const int* __restrict__ eidx,
            const float* __restrict__ epsP, ushortT* __restrict__ z, int N){
  constexpr int QL     = (K/4)/8;         // uint4 chunks per slice row (1 or 2)
  constexpr int SPLITW = 4/QL;            // edge-split ways (4 or 2)
  constexpr int U      = 4;               // edges per predicated batch per lane
  __shared__ int s_row[65];
  __shared__ int s_eidx[ECAP];
  const int t    = threadIdx.x;
  const int tile = blockIdx.x >> 2;
  const int sl   = blockIdx.x & 3;
  const int row0 = tile * 64;

  // stage edge window + row ptrs (coalesced)
  const int e0 = rowptr[min(row0, N)];
  const int e1 = rowptr[min(row0 + 64, N)];
  if (t < 65){
    int idx = row0 + t; if (idx > N) idx = N;
    s_row[t] = rowptr[idx];
  }
  const int cnt = e1 - e0;
  for (int j = t; j < cnt && j < ECAP; j += 256) s_eidx[j] = eidx[e0 + j];
  __syncthreads();

  const int n  = t >> 2;               // node-in-tile
  const int L  = t & 3;
  const int q  = (SPLITW == 4) ? 0 : (L >> 1);
  const int sp = L & (SPLITW - 1);
  const int node = row0 + n;
  const uint4* __restrict__ tbq = tb + (size_t)sl * N * QL + q;

  float acc[8];
  #pragma unroll
  for (int j = 0; j < 8; ++j) acc[j] = 0.f;

  // self term on sp==0 lane (issued first, overlaps the loop)
  if (sp == 0 && node < N){
    const float se = 1.0f + epsP[0];
    uint4 v = tbq[(size_t)node * QL];
    acc[0] = se * b2f_lo(v.x); acc[1] = se * b2f_hi(v.x);
    acc[2] = se * b2f_lo(v.y); acc[3] = se * b2f_hi(v.y);
    acc[4] = se * b2f_lo(v.z); acc[5] = se * b2f_hi(v.z);
    acc[6] = se * b2f_lo(v.w); acc[7] = se * b2f_hi(v.w);
  }

  const int b    = s_row[n] - e0;
  const int e    = s_row[n+1] - e0;
  const int iend = min(e, ECAP);       // == e for all real inputs
  // predicated full batches: 4 loads always issued, OOB masked via fmac
  for (int i = b + sp; i < iend; i += SPLITW*U){
    float m[U]; int src[U];
    #pragma unroll
    for (int u = 0; u < U; ++u){
      int ii = i + u*SPLITW;
      m[u]   = (ii < iend) ? 1.f : 0.f;
      src[u] = s_eidx[min(ii, iend-1)];
    }
    uint4 v[U];
    #pragma unroll
    for (int u = 0; u < U; ++u) v[u] = tbq[(size_t)src[u] * QL];
    #pragma unroll
    for (int u = 0; u < U; ++u){
      acc[0] = fmaf(m[u], b2f_lo(v[u].x), acc[0]);
      acc[1] = fmaf(m[u], b2f_hi(v[u].x), acc[1]);
      acc[2] = fmaf(m[u], b2f_lo(v[u].y), acc[2]);
      acc[3] = fmaf(m[u], b2f_hi(v[u].y), acc[3]);
      acc[4] = fmaf(m[u], b2f_lo(v[u].z), acc[4]);
      acc[5] = fmaf(m[u], b2f_hi(v[u].z), acc[5]);
      acc[6] = fmaf(m[u], b2f_lo(v[u].w), acc[6]);
      acc[7] = fmaf(m[u], b2f_hi(v[u].w), acc[7]);
    }
  }
  // overflow tail beyond ECAP (uniform-false for this input) — global eidx
  {
    int i2 = b + sp;
    if (iend > i2) i2 += ((iend - i2 + SPLITW - 1)/SPLITW)*SPLITW;
    for (; i2 < e; i2 += SPLITW){
      int s0 = eidx[e0 + i2];
      uint4 v = tbq[(size_t)s0 * QL];
      acc[0] += b2f_lo(v.x); acc[1] += b2f_hi(v.x);
      acc[2] += b2f_lo(v.y); acc[3] += b2f_hi(v.y);
      acc[4] += b2f_lo(v.z); acc[5] += b2f_hi(v.z);
      acc[6] += b2f_lo(v.w); acc[7] += b2f_hi(v.w);
    }
  }
  // reduce across edge-split lanes (xor within sp bits)
  #pragma unroll
  for (int o = 1; o < SPLITW; o <<= 1)
    #pragma unroll
    for (int j = 0; j < 8; ++j) acc[j] += __shfl_xor(acc[j], o);

  if (sp == 0 && node < N){
    uint4 o;
    o.x = pack2(acc[0], acc[1]); o.y = pack2(acc[2], acc[3]);
    o.z = pack2(acc[4], acc[5]); o.w = pack2(acc[6], acc[7]);
    reinterpret_cast<uint4*>(z)[(size_t)node*(K/8) + sl*QL + q] = o;
  }
}

// ---- k_mlp<K,WRITE_HB4>: z (bf16 [NP][K]) -> relu(z@Wa+ba)@Wb+bb -----------
// block = 512 threads = 8 waves, 64 rows. a-frags read directly from global z.
// MFMA wave w: row-frag w&3, col-frags {2*(w>>2), 2*(w>>2)+1}. C/D map
// (verified): col=lane&15, row=(lane>>4)*4+reg. ht padded stride 72.
// WRITE_HB4: also emit hb4 = bf16(relu(out)) slice-major [4][N][16 bf16].

template<int K, bool WRITE_HB4>
__global__ __launch_bounds__(512)
void k_mlp(const ushortT* __restrict__ z,
           const ushortT* __restrict__ WaT,    // [64][K]  bf16
           const float* __restrict__ ba,       // [64]
           const ushortT* __restrict__ WbT,    // [64][64] bf16
           const float* __restrict__ bb,       // [64]
           float* __restrict__ out,            // [N][64] f32
           ushortT* __restrict__ hb4, int N){
  constexpr int HS = 72;       // ht row stride (ushorts), padded
  __shared__ __align__(16) ushortT ht[64*HS];
  const int t = threadIdx.x;
  const int row0 = blockIdx.x * 64;

  const int w  = t >> 6;            // wave 0..7
  const int l  = t & 63;
  const int lr = l & 15;            // operand m-index
  const int lg = l >> 4;            // k-group
  const int rf = w & 3;             // row fragment
  const int c0 = (w >> 2) * 2;      // first of 2 col fragments

  // ---------- GEMM stage 1: h = relu(z @ Wa + ba) --------------------------
  f32x4 c1[2];
  #pragma unroll
  for (int cl = 0; cl < 2; ++cl){ float bv = ba[(c0+cl)*16 + lr]; c1[cl] = (f32x4){bv,bv,bv,bv}; }
  #pragma unroll
  for (int kf = 0; kf < K/32; ++kf){
    bf16x8 a = *reinterpret_cast<const bf16x8*>(&z[(size_t)(row0 + rf*16 + lr)*K + kf*32 + lg*8]);
    #pragma unroll
    for (int cl = 0; cl < 2; ++cl){
      bf16x8 bfr = *reinterpret_cast<const bf16x8*>(&WaT[((c0+cl)*16 + lr)*K + kf*32 + lg*8]);
      c1[cl] = __builtin_amdgcn_mfma_f32_16x16x32_bf16(a, bfr, c1[cl], 0, 0, 0);
    }
  }
  #pragma unroll
  for (int cl = 0; cl < 2; ++cl)
    #pragma unroll
    for (int r = 0; r < 4; ++r)
      ht[(rf*16 + lg*4 + r)*HS + (c0+cl)*16 + lr] = f2b(fmaxf(c1[cl][r], 0.f));
  __syncthreads();

  // ---------- GEMM stage 2: out = h @ Wb + bb ------------------------------
  f32x4 c2[2];
  #pragma unroll
  for (int cl = 0; cl < 2; ++cl){ float bv = bb[(c0+cl)*16 + lr]; c2[cl] = (f32x4){bv,bv,bv,bv}; }
  #pragma unroll
  for (int kf = 0; kf < 2; ++kf){
    bf16x8 a = *reinterpret_cast<const bf16x8*>(&ht[(rf*16 + lr)*HS + kf*32 + lg*8]);
    #pragma unroll
    for (int cl = 0; cl < 2; ++cl){
      bf16x8 bfr = *reinterpret_cast<const bf16x8*>(&WbT[((c0+cl)*16 + lr)*64 + kf*32 + lg*8]);
      c2[cl] = __builtin_amdgcn_mfma_f32_16x16x32_bf16(a, bfr, c2[cl], 0, 0, 0);
    }
  }
  #pragma unroll
  for (int cl = 0; cl < 2; ++cl)
    #pragma unroll
    for (int r = 0; r < 4; ++r){
      int row = row0 + rf*16 + lg*4 + r;
      if (row < N){
        float v = c2[cl][r];
        int col = (c0+cl)*16 + lr;
        out[(size_t)row*64 + col] = v;
        if (WRITE_HB4){
          int s2 = col >> 4, f = col & 15;    // slice, feat-in-slice
          hb4[(size_t)s2*N*16 + (size_t)row*16 + f] = f2b(fmaxf(v, 0.f));
        }
      }
    }
}

// ---- Host ------------------------------------------------------------------

extern "C" void kernel_launch(void* const* d_in, const int* in_sizes, int n_in,
                              void* d_out, int out_size, void* d_ws, size_t ws_size,
                              hipStream_t stream) {
  const int N = in_sizes[0] / NFEAT;
  const int E = in_sizes[1] / 2;
  const int nbkt  = (N + BNODES - 1) / BNODES;  // 196
  const int ntile = (N + 63) / 64;              // 1563
  const int NP    = ntile * 64;                 // padded rows (mlp reads)

  const float* x    = (const float*)d_in[0];
  const int*   ei   = (const int*)d_in[1];
  const int*   srcI = ei;
  const int*   dstI = ei + E;
  const float* eps1 = (const float*)d_in[2];
  const float* eps2 = (const float*)d_in[3];
  const float* W1a  = (const float*)d_in[4];
  const float* b1a  = (const float*)d_in[5];
  const float* W1b  = (const float*)d_in[6];
  const float* b1b  = (const float*)d_in[7];
  const float* W2a  = (const float*)d_in[8];
  const float* b2a  = (const float*)d_in[9];
  const float* W2b  = (const float*)d_in[10];
  const float* b2b  = (const float*)d_in[11];

  float* outLogits = (float*)d_out;                  // [N, NCLS]
  float* outEmb    = outLogits + (size_t)N * HID;    // [N, HID]

  // workspace carve-out (256B aligned)
  char* w = (char*)d_ws;
  size_t off = 0;
  auto alloc = [&](size_t bytes) -> void* {
    void* p = w + off;
    off = (off + bytes + 255) & ~(size_t)255;
    return p;
  };
  int*     rowptr  = (int*)alloc((size_t)(N+1) * sizeof(int));
  int*     eidx    = (int*)alloc((size_t)E * sizeof(int));
  int*     bktCnt  = (int*)alloc((size_t)NBKT_MAX * sizeof(int));
  ushortT* T1a     = (ushortT*)alloc(64*32*sizeof(ushortT));
  ushortT* T1b     = (ushortT*)alloc(64*64*sizeof(ushortT));
  ushortT* T2a     = (ushortT*)alloc(64*64*sizeof(ushortT));
  ushortT* T2b     = (ushortT*)alloc(64*64*sizeof(ushortT));
  // union block: bktData (16.8MB, dead after k_build) then z1b/z2b (19.2MB)
  size_t ubytes = (size_t)NBKT_MAX * BCAP * sizeof(int);
  size_t zbytes = (size_t)NP * (NFEAT + HID) * sizeof(ushortT);
  char*  ublk   = (char*)alloc(ubytes > zbytes ? ubytes : zbytes);
  int*     bktData = (int*)ublk;
  ushortT* z1b     = (ushortT*)ublk;                         // [NP][32] bf16
  ushortT* z2b     = (ushortT*)(ublk + (size_t)NP*NFEAT*2);  // [NP][64] bf16
  uint4*   xb4     = (uint4*)alloc((size_t)4 * N * 16);      // [4][N][16B]
  ushortT* hb4     = (ushortT*)alloc((size_t)4 * N * 16 * sizeof(ushortT)); // [4][N][16]

  // 1) prep: xb4 slice-major bf16, transposed bf16 weights, bktCnt = 0
  const int np = N * 4;
  k_prep<<<(np+255)/256, 256, 0, stream>>>(x, xb4, N, W1a, W1b, W2a, W2b,
                                           T1a, T1b, T2a, T2b, bktCnt, nbkt);

  // 2) CSR build (edge order within a row is atomic-raced -> only permutes
  //    float-sum order; validated R1-R10 at <=1.6e-2 vs 4.7e-2 threshold)
  k_bucket<<<(E+4095)/4096, 256, 0, stream>>>(srcI, dstI, E, N, nbkt, bktCnt, bktData);
  k_build <<<nbkt, BNODES, 0, stream>>>(bktCnt, bktData, nbkt, rowptr, eidx, N);

  // 3) layer 1: sliced gather -> z1b; MFMA MLP -> emb f32 + hb4 (slice-major)
  k_gath<NFEAT><<<ntile*4, 256, 0, stream>>>(xb4, rowptr, eidx, eps1, z1b, N);
  k_mlp<NFEAT, true><<<ntile, 512, 0, stream>>>(z1b, T1a, b1a, T1b, b1b, outEmb, hb4, N);

  // 4) layer 2: sliced gather hb4 -> z2b; MFMA MLP -> logits
  k_gath<HID><<<ntile*4, 256, 0, stream>>>((const uint4*)hb4, rowptr, eidx, eps2, z2b, N);
  k_mlp<HID, false><<<ntile, 512, 0, stream>>>(z2b, T2a, b2a, T2b, b2b, outLogits, (ushortT*)nullptr, N);
}

// Round 12
// 124.066 us; speedup vs baseline: 1.2952x; 1.2952x over previous
//
#include <hip/hip_runtime.h>

// GIN 2-layer forward.  N=100000 nodes, E=1600000 edges, NF=32, HC=NC=64.
// R12: isolate the R6-vs-R8 gather-loop delta. R6 (2-loop LDS-only gather)
// ran ~31us/layer; R8 (3-loop: clamp + LDS cleanup + global overflow tail)
// ran 42us. This round = R8 pipeline with R6's exact hot-loop shape; the
// cnt>ECAP case (statistically unreachable, input-fixed) is a block-uniform
// fallback branch instead of per-iteration clamps.

#define NFEAT 32
#define HID   64
#define NCLS  64

#define BSH   9                 // bucket = dst >> 9  (512 nodes per bucket)
#define BNODES 512
#define NBKT_MAX 256            // supports N <= 131072
#define BCAP  16384             // slots per bucket (mean 8192 for uniform E=1.6M)
#define ECAP  2048              // LDS-staged edges per 64-node fused block (mean 1024)

typedef unsigned int uint;
typedef unsigned short ushortT;
typedef __attribute__((ext_vector_type(8))) short bf16x8;   // 8 bf16 = 4 VGPR
typedef __attribute__((ext_vector_type(4))) float f32x4;

__device__ __forceinline__ int clampi(int v, int hi){ v = v < 0 ? 0 : v; return v > hi ? hi : v; }

// round-to-nearest-even f32 -> bf16 (as ushort)
__device__ __forceinline__ ushortT f2b(float f){
  uint u = __float_as_uint(f);
  u = (u + 0x7FFFu + ((u >> 16) & 1u)) >> 16;
  return (ushortT)u;
}
__device__ __forceinline__ float b2f_lo(uint u){ return __uint_as_float(u << 16); }
__device__ __forceinline__ float b2f_hi(uint u){ return __uint_as_float(u & 0xFFFF0000u); }
__device__ __forceinline__ uint pack2(float lo, float hi){
  return (uint)f2b(lo) | ((uint)f2b(hi) << 16);
}

// ---- k_prep: xb = bf16(x); transposed bf16 weights; zero bktCnt ------------

__global__ void k_prep(const float* __restrict__ x, ushortT* __restrict__ xb, int n4,
                       const float* __restrict__ W1a, const float* __restrict__ W1b,
                       const float* __restrict__ W2a, const float* __restrict__ W2b,
                       ushortT* __restrict__ T1a, ushortT* __restrict__ T1b,
                       ushortT* __restrict__ T2a, ushortT* __restrict__ T2b,
                       int* __restrict__ bktCnt, int nbkt){
  int t = blockIdx.x*256 + threadIdx.x;
  if (t < n4){
    float4 v = reinterpret_cast<const float4*>(x)[t];
    ushort4 o = { f2b(v.x), f2b(v.y), f2b(v.z), f2b(v.w) };
    reinterpret_cast<ushort4*>(xb)[t] = o;
  }
  if (t < nbkt) bktCnt[t] = 0;
  if (t < 14336){
    const float* W; ushortT* T; int K; int base;
    if      (t <  2048){ W=W1a; T=T1a; K=32; base=0;     }
    else if (t <  6144){ W=W1b; T=T1b; K=64; base=2048;  }
    else if (t < 10240){ W=W2a; T=T2a; K=64; base=6144;  }
    else               { W=W2b; T=T2b; K=64; base=10240; }
    int o = t - base;
    int k = o >> 6, c = o & 63;        // all matrices have 64 columns
    T[c*K + k] = f2b(W[o]);
  }
}

// ---- Pass A: bucket edges by dst>>9, packed val = (dstLow9<<17)|src --------

__global__ void k_bucket(const int* __restrict__ src, const int* __restrict__ dst,
                         int E, int N, int nbkt,
                         int* __restrict__ bktCnt, int* __restrict__ bktData){
  __shared__ int s_cnt[NBKT_MAX];
  __shared__ int s_base[NBKT_MAX];
  const int t = threadIdx.x;
  for (int j = t; j < nbkt; j += 256) s_cnt[j] = 0;
  __syncthreads();

  const int e0 = blockIdx.x * 4096;
  const int e1 = min(e0 + 4096, E);
  for (int e = e0 + t; e < e1; e += 256){
    int d = clampi(dst[e], N-1);
    atomicAdd(&s_cnt[d >> BSH], 1);
  }
  __syncthreads();
  for (int j = t; j < nbkt; j += 256){
    int c = s_cnt[j];
    s_base[j] = (c > 0) ? atomicAdd(&bktCnt[j], c) : 0;
    s_cnt[j] = 0;                     // reuse as local cursor
  }
  __syncthreads();
  for (int e = e0 + t; e < e1; e += 256){
    int d = clampi(dst[e], N-1);
    int s = clampi(src[e], N-1);
    int b = d >> BSH;
    int p = s_base[b] + atomicAdd(&s_cnt[b], 1);
    if (p < BCAP)                     // statistically unreachable; UB guard
      bktData[(size_t)b * BCAP + p] = ((d & (BNODES-1)) << 17) | s;
  }
}

// ---- Pass B: per-bucket CSR fill; bucket prefix computed in-block ----------

__global__ __launch_bounds__(BNODES)
void k_build(const int* __restrict__ bktCnt, const int* __restrict__ bktData,
             int nbkt, int* __restrict__ rowptr, int* __restrict__ eidx, int N){
  __shared__ int s_bs[NBKT_MAX];
  __shared__ int s_h[BNODES];
  __shared__ int s_cur[BNODES];
  const int b = blockIdx.x, t = threadIdx.x;

  if (t < NBKT_MAX) s_bs[t] = (t < nbkt) ? min(bktCnt[t], BCAP) : 0;
  __syncthreads();
  for (int off = 1; off < NBKT_MAX; off <<= 1){
    int add = 0;
    if (t < NBKT_MAX && t >= off) add = s_bs[t-off];
    __syncthreads();
    if (t < NBKT_MAX) s_bs[t] += add;
    __syncthreads();
  }
  const int cnt  = min(bktCnt[b], BCAP);
  const int base = s_bs[b] - cnt;     // exclusive prefix
  if (b == 0 && t == 0) rowptr[N] = s_bs[nbkt-1];
  const int* __restrict__ data = bktData + (size_t)b * BCAP;

  s_h[t] = 0;
  __syncthreads();
  for (int e = t; e < cnt; e += BNODES) atomicAdd(&s_h[data[e] >> 17], 1);
  __syncthreads();

  int deg = s_h[t];
  for (int off = 1; off < BNODES; off <<= 1){     // inclusive scan over nodes
    int add = (t >= off) ? s_h[t-off] : 0;
    __syncthreads();
    s_h[t] += add;
    __syncthreads();
  }
  int excl = s_h[t] - deg;
  int node = b * BNODES + t;
  if (node < N) rowptr[node] = base + excl;
  s_cur[t] = excl;
  __syncthreads();

  for (int e = t; e < cnt; e += BNODES){
    int val = data[e];
    int d = val >> 17;
    int p = atomicAdd(&s_cur[d], 1);
    eidx[base + p] = val & 0x1FFFF;
  }
}

// ---- fused layer: gather z -> LDS, then z@Wa -> relu -> @Wb (MFMA) ---------
// block = 512 threads = 8 waves, 64 nodes (8 lanes/node = 2 edge-split x
// 4 col-lanes). Hot path (cnt<=ECAP, always true for this input): R6's exact
// two-loop LDS-only gather — batched U-loop + serial cleanup, no clamps, no
// global tail. cnt>ECAP falls to a block-uniform all-global gather branch.
// MFMA: wave w owns row-frag w&3, col-frags {2*(w>>2), 2*(w>>2)+1}. C/D map
// (verified): col=lane&15, row=(lane>>4)*4+reg; identical (lane,slot)->k
// maps for a/b operands make internal k-order cancel. zt/ht padded.

template<int K, bool WRITE_HB>
__global__ __launch_bounds__(512)
void k_fused(const uint4* __restrict__ f4,       // featb as uint4 rows [N][K/8]
             const int* __restrict__ rowptr, const int* __restrict__ eidx,
             const float* __restrict__ epsP,
             const ushortT* __restrict__ WaT,    // [64][K]  bf16
             const float* __restrict__ ba,       // [64]
             const ushortT* __restrict__ WbT,    // [64][64] bf16
             const float* __restrict__ bb,       // [64]
             float* __restrict__ out,            // [N][64] f32
             ushortT* __restrict__ hb, int N){
  constexpr int RS = K/8;      // uint4 per feature row (4 or 8)
  constexpr int CH = RS/4;     // uint4 per col-lane per edge (1 or 2)
  constexpr int U  = (CH == 1) ? 4 : 2;   // edges/batch (U*CH = 4 loads in flight)
  constexpr int ZS = K + 8;    // zt row stride (ushorts), +16B pad
  constexpr int HS = 72;       // ht row stride (ushorts), +16B pad
  __shared__ int s_row[65];
  __shared__ int s_eidx[ECAP];
  __shared__ __align__(16) ushortT zt[64*ZS];
  __shared__ __align__(16) ushortT ht[64*HS];
  const int t = threadIdx.x;
  const int row0 = blockIdx.x * 64;

  // ---------- stage edge window + row ptrs (coalesced) ---------------------
  const int e0 = rowptr[min(row0, N)];
  const int e1 = rowptr[min(row0 + 64, N)];
  if (t < 65){
    int idx = row0 + t; if (idx > N) idx = N;
    s_row[t] = rowptr[idx] - e0;     // block-relative
  }
  const int cnt = e1 - e0;
  for (int j = t; j < cnt && j < ECAP; j += 512) s_eidx[j] = eidx[e0 + j];
  __syncthreads();

  // ---------- gather phase: 8 lanes/node ------------------------------------
  {
    const int n = t >> 3;            // node-in-block
    const int L = t & 7;
    const int q = L & 3;             // col-chunk lane
    const int s = L >> 2;            // edge split (0/1)
    const int node = row0 + n;
    float acc[CH*8];
    #pragma unroll
    for (int j = 0; j < CH*8; ++j) acc[j] = 0.f;

    const int b = s_row[n];
    const int e = s_row[n+1];

    if (cnt <= ECAP){
      // ---- hot path: R6-exact two-loop LDS-only gather ----
      int i = b + s;
      for (; i + 2*(U-1) < e; i += 2*U){
        int src[U];
        #pragma unroll
        for (int u = 0; u < U; ++u) src[u] = s_eidx[i + 2*u];
        uint4 v[U][CH];
        #pragma unroll
        for (int u = 0; u < U; ++u)
          #pragma unroll
          for (int c = 0; c < CH; ++c)
            v[u][c] = f4[(size_t)src[u]*RS + q*CH + c];
        #pragma unroll
        for (int u = 0; u < U; ++u)
          #pragma unroll
          for (int c = 0; c < CH; ++c){
            acc[c*8+0] += b2f_lo(v[u][c].x); acc[c*8+1] += b2f_hi(v[u][c].x);
            acc[c*8+2] += b2f_lo(v[u][c].y); acc[c*8+3] += b2f_hi(v[u][c].y);
            acc[c*8+4] += b2f_lo(v[u][c].z); acc[c*8+5] += b2f_hi(v[u][c].z);
            acc[c*8+6] += b2f_lo(v[u][c].w); acc[c*8+7] += b2f_hi(v[u][c].w);
          }
      }
      for (; i < e; i += 2){
        int src0 = s_eidx[i];
        #pragma unroll
        for (int c = 0; c < CH; ++c){
          uint4 v = f4[(size_t)src0*RS + q*CH + c];
          acc[c*8+0] += b2f_lo(v.x); acc[c*8+1] += b2f_hi(v.x);
          acc[c*8+2] += b2f_lo(v.y); acc[c*8+3] += b2f_hi(v.y);
          acc[c*8+4] += b2f_lo(v.z); acc[c*8+5] += b2f_hi(v.z);
          acc[c*8+6] += b2f_lo(v.w); acc[c*8+7] += b2f_hi(v.w);
        }
      }
    } else {
      // ---- fallback (block-uniform, unreachable for this input) ----
      for (int i = b + s; i < e; i += 2){
        int src0 = eidx[e0 + i];
        #pragma unroll
        for (int c = 0; c < CH; ++c){
          uint4 v = f4[(size_t)src0*RS + q*CH + c];
          acc[c*8+0] += b2f_lo(v.x); acc[c*8+1] += b2f_hi(v.x);
          acc[c*8+2] += b2f_lo(v.y); acc[c*8+3] += b2f_hi(v.y);
          acc[c*8+4] += b2f_lo(v.z); acc[c*8+5] += b2f_hi(v.z);
          acc[c*8+6] += b2f_lo(v.w); acc[c*8+7] += b2f_hi(v.w);
        }
      }
    }

    if (s == 1 && node < N){          // self term on split-1 lanes
      const float se = 1.0f + epsP[0];
      #pragma unroll
      for (int c = 0; c < CH; ++c){
        uint4 v = f4[(size_t)node*RS + q*CH + c];
        acc[c*8+0] = fmaf(se, b2f_lo(v.x), acc[c*8+0]);
        acc[c*8+1] = fmaf(se, b2f_hi(v.x), acc[c*8+1]);
        acc[c*8+2] = fmaf(se, b2f_lo(v.y), acc[c*8+2]);
        acc[c*8+3] = fmaf(se, b2f_hi(v.y), acc[c*8+3]);
        acc[c*8+4] = fmaf(se, b2f_lo(v.z), acc[c*8+4]);
        acc[c*8+5] = fmaf(se, b2f_hi(v.z), acc[c*8+5]);
        acc[c*8+6] = fmaf(se, b2f_lo(v.w), acc[c*8+6]);
        acc[c*8+7] = fmaf(se, b2f_hi(v.w), acc[c*8+7]);
      }
    }
    #pragma unroll
    for (int j = 0; j < CH*8; ++j) acc[j] += __shfl_xor(acc[j], 4);
    if (s == 0){
      #pragma unroll
      for (int c = 0; c < CH; ++c){
        uint4 z;
        z.x = pack2(acc[c*8+0], acc[c*8+1]);
        z.y = pack2(acc[c*8+2], acc[c*8+3]);
        z.z = pack2(acc[c*8+4], acc[c*8+5]);
        z.w = pack2(acc[c*8+6], acc[c*8+7]);
        *reinterpret_cast<uint4*>(&zt[n*ZS + (q*CH + c)*8]) = z;
      }
    }
  }
  __syncthreads();

  // ---------- GEMM stage 1: h = relu(z @ Wa + ba) --------------------------
  const int w  = t >> 6;            // wave 0..7
  const int l  = t & 63;
  const int lr = l & 15;            // operand m-index
  const int lg = l >> 4;            // k-group
  const int rf = w & 3;             // row fragment
  const int c0 = (w >> 2) * 2;      // first of 2 col fragments
  f32x4 c1[2];
  #pragma unroll
  for (int cl = 0; cl < 2; ++cl){ float bv = ba[(c0+cl)*16 + lr]; c1[cl] = (f32x4){bv,bv,bv,bv}; }
  #pragma unroll
  for (int kf = 0; kf < K/32; ++kf){
    bf16x8 a = *reinterpret_cast<const bf16x8*>(&zt[(rf*16 + lr)*ZS + kf*32 + lg*8]);
    #pragma unroll
    for (int cl = 0; cl < 2; ++cl){
      bf16x8 bfr = *reinterpret_cast<const bf16x8*>(&WaT[((c0+cl)*16 + lr)*K + kf*32 + lg*8]);
      c1[cl] = __builtin_amdgcn_mfma_f32_16x16x32_bf16(a, bfr, c1[cl], 0, 0, 0);
    }
  }
  #pragma unroll
  for (int cl = 0; cl < 2; ++cl)
    #pragma unroll
    for (int r = 0; r < 4; ++r)
      ht[(rf*16 + lg*4 + r)*HS + (c0+cl)*16 + lr] = f2b(fmaxf(c1[cl][r], 0.f));
  __syncthreads();

  // ---------- GEMM stage 2: out = h @ Wb + bb ------------------------------
  f32x4 c2[2];
  #pragma unroll
  for (int cl = 0; cl < 2; ++cl){ float bv = bb[(c0+cl)*16 + lr]; c2[cl] = (f32x4){bv,bv,bv,bv}; }
  #pragma unroll
  for (int kf = 0; kf < 2; ++kf){
    bf16x8 a = *reinterpret_cast<const bf16x8*>(&ht[(rf*16 + lr)*HS + kf*32 + lg*8]);
    #pragma unroll
    for (int cl = 0; cl < 2; ++cl){
      bf16x8 bfr = *reinterpret_cast<const bf16x8*>(&WbT[((c0+cl)*16 + lr)*64 + kf*32 + lg*8]);
      c2[cl] = __builtin_amdgcn_mfma_f32_16x16x32_bf16(a, bfr, c2[cl], 0, 0, 0);
    }
  }
  #pragma unroll
  for (int cl = 0; cl < 2; ++cl)
    #pragma unroll
    for (int r = 0; r < 4; ++r){
      int row = row0 + rf*16 + lg*4 + r;
      if (row < N){
        float v = c2[cl][r];
        out[(size_t)row*64 + (c0+cl)*16 + lr] = v;
        if (WRITE_HB) hb[(size_t)row*64 + (c0+cl)*16 + lr] = f2b(fmaxf(v, 0.f));
      }
    }
}

// ---- Host ------------------------------------------------------------------

extern "C" void kernel_launch(void* const* d_in, const int* in_sizes, int n_in,
                              void* d_out, int out_size, void* d_ws, size_t ws_size,
                              hipStream_t stream) {
  const int N = in_sizes[0] / NFEAT;
  const int E = in_sizes[1] / 2;
  const int nbkt = (N + BNODES - 1) / BNODES;   // 196 for N=100000

  const float* x    = (const float*)d_in[0];
  const int*   ei   = (const int*)d_in[1];
  const int*   srcI = ei;
  const int*   dstI = ei + E;
  const float* eps1 = (const float*)d_in[2];
  const float* eps2 = (const float*)d_in[3];
  const float* W1a  = (const float*)d_in[4];
  const float* b1a  = (const float*)d_in[5];
  const float* W1b  = (const float*)d_in[6];
  const float* b1b  = (const float*)d_in[7];
  const float* W2a  = (const float*)d_in[8];
  const float* b2a  = (const float*)d_in[9];
  const float* W2b  = (const float*)d_in[10];
  const float* b2b  = (const float*)d_in[11];

  float* outLogits = (float*)d_out;                  // [N, NCLS]
  float* outEmb    = outLogits + (size_t)N * HID;    // [N, HID]

  // workspace carve-out (256B aligned)
  char* w = (char*)d_ws;
  size_t off = 0;
  auto alloc = [&](size_t bytes) -> void* {
    void* p = w + off;
    off = (off + bytes + 255) & ~(size_t)255;
    return p;
  };
  int*     rowptr  = (int*)alloc((size_t)(N+1) * sizeof(int));
  int*     eidx    = (int*)alloc((size_t)E * sizeof(int));
  int*     bktCnt  = (int*)alloc((size_t)NBKT_MAX * sizeof(int));
  ushortT* T1a     = (ushortT*)alloc(64*32*sizeof(ushortT));
  ushortT* T1b     = (ushortT*)alloc(64*64*sizeof(ushortT));
  ushortT* T2a     = (ushortT*)alloc(64*64*sizeof(ushortT));
  ushortT* T2b     = (ushortT*)alloc(64*64*sizeof(ushortT));
  int*     bktData = (int*)alloc((size_t)NBKT_MAX * BCAP * sizeof(int));  // 16.8MB
  ushortT* xb      = (ushortT*)alloc((size_t)N * NFEAT * sizeof(ushortT));
  ushortT* hb      = (ushortT*)alloc((size_t)N * HID * sizeof(ushortT));

  // 1) prep: xb = bf16(x), transposed bf16 weights, bktCnt = 0   (one dispatch)
  const int n4 = N * NFEAT / 4;
  k_prep<<<(n4+255)/256, 256, 0, stream>>>(x, xb, n4, W1a, W1b, W2a, W2b,
                                           T1a, T1b, T2a, T2b, bktCnt, nbkt);

  // 2) CSR build (edge order within a row is atomic-raced -> only permutes
  //    float-sum order; validated R1-R11 at <=1.6e-2 vs 4.7e-2 threshold)
  k_bucket<<<(E+4095)/4096, 256, 0, stream>>>(srcI, dstI, E, N, nbkt, bktCnt, bktData);
  k_build <<<nbkt, BNODES, 0, stream>>>(bktCnt, bktData, nbkt, rowptr, eidx, N);

  // 3) layer 1 fused: gather xb -> z1 -> MFMA MLP -> emb f32 + hb=bf16(relu)
  const int nblk = (N + 63) / 64;
  k_fused<NFEAT, true><<<nblk, 512, 0, stream>>>((const uint4*)xb, rowptr, eidx,
      eps1, T1a, b1a, T1b, b1b, outEmb, hb, N);

  // 4) layer 2 fused: gather hb -> z2 -> MFMA MLP -> logits f32
  k_fused<HID, false><<<nblk, 512, 0, stream>>>((const uint4*)hb, rowptr, eidx,
      eps2, T2a, b2a, T2b, b2b, outLogits, (ushortT*)nullptr, N);
}